// Round 1
// baseline (118106.799 us; speedup 1.0000x reference)
//
#include <hip/hip_runtime.h>

#define GWG 256      // workgroups (1 per CU)
#define BTH 768      // threads per WG (12 waves)
#define WROW 2056    // padded LDS row pitch for Wih1 (bf16 elems): 2048 + 8
#define LDSZ 120640

// ---------- helpers ----------
__device__ __forceinline__ unsigned short b16(float f) {   // f32 -> bf16 (RNE)
  union { float f; unsigned int i; } z; z.f = f;
  unsigned int r = z.i + 0x7fffu + ((z.i >> 16) & 1u);
  return (unsigned short)(r >> 16);
}
__device__ __forceinline__ float bup(unsigned short u) {   // bf16 -> f32
  union { unsigned int i; float f; } z; z.i = ((unsigned int)u) << 16; return z.f;
}
__device__ __forceinline__ float blo(unsigned int p) {
  union { unsigned int i; float f; } z; z.i = p << 16; return z.f;
}
__device__ __forceinline__ float bhi(unsigned int p) {
  union { unsigned int i; float f; } z; z.i = p & 0xffff0000u; return z.f;
}
__device__ __forceinline__ float sigm(float x) { return 1.f / (1.f + expf(-x)); }

__device__ __forceinline__ void gbar(int* bar) {
  __syncthreads();
  if (threadIdx.x == 0) {
    __builtin_amdgcn_fence(__ATOMIC_RELEASE, "agent");
    int old = __hip_atomic_fetch_add(bar, 1, __ATOMIC_RELAXED, __HIP_MEMORY_SCOPE_AGENT);
    int tgt = (old & ~(GWG - 1)) + GWG;       // monotone-counter barrier
    while (__hip_atomic_load(bar, __ATOMIC_RELAXED, __HIP_MEMORY_SCOPE_AGENT) < tgt)
      __builtin_amdgcn_s_sleep(1);
    __builtin_amdgcn_fence(__ATOMIC_ACQUIRE, "agent");
  }
  __syncthreads();
}

// ---------- pre-kernels ----------
__global__ __launch_bounds__(256) void prep(const float* __restrict__ bih0, const float* __restrict__ bhh0,
                                            const float* __restrict__ bih1, const float* __restrict__ bhh1,
                                            float* __restrict__ b0, float* __restrict__ b1f, int* bar) {
  int i = blockIdx.x * 256 + threadIdx.x;
  if (i < 8192) { b0[i] = bih0[i] + bhh0[i]; b1f[i] = bih1[i] + bhh1[i]; }
  if (i == 0) *bar = 0;
}

__global__ __launch_bounds__(256) void transpose_wx(const float* __restrict__ Wih0, float* __restrict__ WxT) {
  int idx = blockIdx.x * 256 + threadIdx.x;          // 360*8192 total
  int r = idx & 8191, k = idx >> 13;
  WxT[(size_t)k * 8192 + r] = Wih0[(size_t)r * 424 + k];
}

// gates_x = inputVecs @ Wx^T + b0, stored bf16, only gate rows {i,g,o}
__global__ __launch_bounds__(256) void gemm_gx(const float* __restrict__ inV, const float* __restrict__ WxT,
                                               const float* __restrict__ b0, unsigned short* __restrict__ gxb) {
  __shared__ float lin[32 * 360];
  int t0 = blockIdx.x * 32;
  int by = blockIdx.y;                 // 0..23
  int ry = by >> 3;
  int gatey = ry + (ry ? 1 : 0);       // {0,2,3}
  int r = gatey * 2048 + (by & 7) * 256 + threadIdx.x;
  for (int i = threadIdx.x; i < 32 * 360; i += 256) lin[i] = inV[(size_t)t0 * 360 + i];
  __syncthreads();
  float b = b0[r];
  float acc[32];
#pragma unroll
  for (int tt = 0; tt < 32; ++tt) acc[tt] = b;
  for (int k = 0; k < 360; k += 4) {
    float w0 = WxT[(size_t)(k + 0) * 8192 + r];
    float w1 = WxT[(size_t)(k + 1) * 8192 + r];
    float w2 = WxT[(size_t)(k + 2) * 8192 + r];
    float w3 = WxT[(size_t)(k + 3) * 8192 + r];
#pragma unroll
    for (int tt = 0; tt < 32; ++tt) {
      float4 l = *reinterpret_cast<const float4*>(&lin[tt * 360 + k]);
      acc[tt] = fmaf(w0, l.x, fmaf(w1, l.y, fmaf(w2, l.z, fmaf(w3, l.w, acc[tt]))));
    }
  }
  for (int tt = 0; tt < 32; ++tt) gxb[(size_t)(t0 + tt) * 8192 + r] = b16(acc[tt]);
}

// ---------- persistent scan kernel ----------
struct KP {
  const float* Wih0; const float* Wih1; const float* Wlin; const float* blin;
  const float* Wmap; const float* bmap; const float* embed0; const float* b1f;
  const unsigned short* gxb;
  float* h0buf; float* h1buf; float* out; int* bar;
};

__global__ __launch_bounds__(BTH, 3) void lstm_seq(KP p) {
  extern __shared__ __align__(16) char smem[];
  unsigned short* lW1 = (unsigned short*)smem;                  // 24 x WROW   (Wih1 slice)
  unsigned short* lWe = (unsigned short*)(smem + 98688);        // 24 x 64     (We slice)
  unsigned short* lWl = (unsigned short*)(smem + 101760);       // 2 x 2048    (Wlin rows)
  float* lH = (float*)(smem + 109952);                          // 2048 (h0 / h1)
  float* lY = (float*)(smem + 118144);                          // 512
  float* lE = (float*)(smem + 120192);                          // 64
  float* lR = (float*)(smem + 120448);                          // 24 (+pad)
  float* lV = (float*)(smem + 120576);                          // 16

  const int w = blockIdx.x, tid = threadIdx.x;
  const int rl = tid >> 5;          // 0..23 (row within WG)
  const int l32 = tid & 31;
  const int g3 = rl >> 3;
  const int gate = g3 + (g3 ? 1 : 0);      // {0,2,3} = i,g,o
  const int gr = w * 8 + (rl & 7) + 2048 * gate;

  // ---- stage weights into LDS (once) ----
  for (int r2 = 0; r2 < 24; ++r2) {
    int gg = r2 >> 3; int grr = w * 8 + (r2 & 7) + 2048 * (gg + (gg ? 1 : 0));
    const float* src = p.Wih1 + (size_t)grr * 2048;
    for (int i = tid; i < 2048; i += BTH) lW1[r2 * WROW + i] = b16(src[i]);
  }
  for (int i = tid; i < 24 * 64; i += BTH) {
    int r2 = i >> 6, k = i & 63; int gg = r2 >> 3;
    int grr = w * 8 + (r2 & 7) + 2048 * (gg + (gg ? 1 : 0));
    lWe[r2 * 64 + k] = b16(p.Wih0[(size_t)grr * 424 + 360 + k]);
  }
  for (int i = tid; i < 2 * 2048; i += BTH) {
    int q = i >> 11, k = i & 2047;
    lWl[i] = b16(p.Wlin[(size_t)(w * 2 + q) * 2048 + k]);
  }
  unsigned int wm[32];               // Wmap fragment in VGPRs (pre-rotated)
  float bm = 0.f;
  {
    int e = tid >> 3, l8 = tid & 7;
    if (tid < 512) {
      bm = p.bmap[e];
#pragma unroll
      for (int i = 0; i < 32; ++i) {
        int ii = (i + l8 * 4) & 31;
        int k = e * 512 + l8 * 64 + 2 * ii;
        wm[i] = ((unsigned int)b16(p.Wmap[k + 1]) << 16) | (unsigned int)b16(p.Wmap[k]);
      }
    } else {
#pragma unroll
      for (int i = 0; i < 32; ++i) wm[i] = 0u;
    }
  }
  const float b1r = p.b1f[gr];
  const float bl0 = p.blin[w * 2], bl1 = p.blin[w * 2 + 1];
  __syncthreads();

  for (int t = 0; t < 4096; ++t) {
    // ---------- phase P: lse + embed (redundant per WG) ----------
    if (t == 0) {
      if (tid < 64) lE[tid] = p.embed0[tid];
    } else {
      float v = 0.f, m = -1e30f, s = 0.f;
      if (tid < 512) {
        v = p.out[(size_t)(t - 1) * 512 + tid];
        m = v;
#pragma unroll
        for (int d = 1; d < 64; d <<= 1) m = fmaxf(m, __shfl_xor(m, d));
        if ((tid & 63) == 0) lV[tid >> 6] = m;
      }
      __syncthreads();
      m = fmaxf(fmaxf(fmaxf(lV[0], lV[1]), fmaxf(lV[2], lV[3])),
                fmaxf(fmaxf(lV[4], lV[5]), fmaxf(lV[6], lV[7])));
      if (tid < 512) {
        s = expf(v - m);
#pragma unroll
        for (int d = 1; d < 64; d <<= 1) s += __shfl_xor(s, d);
      }
      __syncthreads();
      if (tid < 512 && (tid & 63) == 0) lV[tid >> 6] = s;
      __syncthreads();
      float lse = m + logf(lV[0] + lV[1] + lV[2] + lV[3] + lV[4] + lV[5] + lV[6] + lV[7]);
      if (tid < 512) lY[tid] = v - lse;
      __syncthreads();
      if (tid < 512) {
        int l8 = tid & 7, base = l8 * 64;
        float acc = 0.f;
#pragma unroll
        for (int i = 0; i < 32; ++i) {
          int k = base + 2 * ((i + l8 * 4) & 31);
          float2 yv = *(const float2*)&lY[k];
          acc = fmaf(blo(wm[i]), yv.x, fmaf(bhi(wm[i]), yv.y, acc));
        }
        acc += __shfl_xor(acc, 1); acc += __shfl_xor(acc, 2); acc += __shfl_xor(acc, 4);
        if (l8 == 0) lE[tid >> 3] = acc + bm;
      }
    }
    __syncthreads();
    // ---------- gates0 -> h0 ----------
    {
      unsigned int uwp = *(const unsigned int*)&lWe[rl * 64 + l32 * 2];
      float2 ev = *(const float2*)&lE[l32 * 2];
      float a = fmaf(blo(uwp), ev.x, bhi(uwp) * ev.y);
      a += __shfl_xor(a, 1); a += __shfl_xor(a, 2); a += __shfl_xor(a, 4);
      a += __shfl_xor(a, 8); a += __shfl_xor(a, 16);
      if (l32 == 0) lR[rl] = a + bup(p.gxb[(size_t)t * 8192 + gr]);
    }
    __syncthreads();
    if (tid < 8) {
      float c = sigm(lR[tid]) * tanhf(lR[8 + tid]);
      float h = sigm(lR[16 + tid]) * tanhf(c);
      p.h0buf[w * 8 + tid] = h;
    }
    gbar(p.bar);   // A: h0 all-gather
    // ---------- gates1 -> h1 ----------
    if (tid < 512) *(float4*)&lH[tid * 4] = *(const float4*)&p.h0buf[tid * 4];
    __syncthreads();
    {
      float acc = 0.f;
      const unsigned short* wr = lW1 + rl * WROW;
#pragma unroll 4
      for (int mm = 0; mm < 16; ++mm) {
        int k = l32 * 4 + mm * 128;
        ushort4 uw = *(const ushort4*)&wr[k];
        float4 hv = *(const float4*)&lH[k];
        acc = fmaf(bup(uw.x), hv.x, acc);
        acc = fmaf(bup(uw.y), hv.y, acc);
        acc = fmaf(bup(uw.z), hv.z, acc);
        acc = fmaf(bup(uw.w), hv.w, acc);
      }
      acc += __shfl_xor(acc, 1); acc += __shfl_xor(acc, 2); acc += __shfl_xor(acc, 4);
      acc += __shfl_xor(acc, 8); acc += __shfl_xor(acc, 16);
      if (l32 == 0) lR[rl] = acc + b1r;
    }
    __syncthreads();
    if (tid < 8) {
      float c = sigm(lR[tid]) * tanhf(lR[8 + tid]);
      float h = sigm(lR[16 + tid]) * tanhf(c);
      p.h1buf[w * 8 + tid] = h;
    }
    gbar(p.bar);   // B: h1 all-gather
    // ---------- y = Wlin @ h1 + blin (2 rows per WG) ----------
    if (tid < 512) *(float4*)&lH[tid * 4] = *(const float4*)&p.h1buf[tid * 4];
    __syncthreads();
    if (tid < 512) {
      int q = tid >> 8, l = tid & 255;
      float a = 0.f;
#pragma unroll
      for (int c2 = 0; c2 < 2; ++c2) {
        int k = c2 * 1024 + l * 4;
        ushort4 uw = *(const ushort4*)&lWl[q * 2048 + k];
        float4 hv = *(const float4*)&lH[k];
        a = fmaf(bup(uw.x), hv.x, fmaf(bup(uw.y), hv.y, fmaf(bup(uw.z), hv.z, fmaf(bup(uw.w), hv.w, a))));
      }
#pragma unroll
      for (int d = 1; d < 64; d <<= 1) a += __shfl_xor(a, d);
      if ((tid & 63) == 0) lV[tid >> 6] = a;
    }
    __syncthreads();
    if (tid < 2) {
      float y = lV[tid * 4] + lV[tid * 4 + 1] + lV[tid * 4 + 2] + lV[tid * 4 + 3] + (tid ? bl1 : bl0);
      p.out[(size_t)t * 512 + w * 2 + tid] = y;
    }
    gbar(p.bar);   // C: y all-gather
  }
}

// ---------- host ----------
extern "C" void kernel_launch(void* const* d_in, const int* in_sizes, int n_in,
                              void* d_out, int out_size, void* d_ws, size_t ws_size,
                              hipStream_t stream) {
  const float* inV  = (const float*)d_in[0];
  const float* Wih0 = (const float*)d_in[1];
  const float* bih0 = (const float*)d_in[2];
  const float* bhh0 = (const float*)d_in[3];
  const float* Wih1 = (const float*)d_in[4];
  const float* bih1 = (const float*)d_in[5];
  const float* bhh1 = (const float*)d_in[6];
  const float* Wlin = (const float*)d_in[7];
  const float* blin = (const float*)d_in[8];
  const float* Wmap = (const float*)d_in[9];
  const float* bmap = (const float*)d_in[10];
  const float* emb0 = (const float*)d_in[11];

  char* ws = (char*)d_ws;
  unsigned short* gxb = (unsigned short*)(ws);            // 4096*8192*2 = 67,108,864
  float* WxT   = (float*)(ws + 67108864);                 // 360*8192*4 = 11,796,480
  float* b0    = (float*)(ws + 78905344);                 // 8192*4
  float* b1f   = (float*)(ws + 78938112);                 // 8192*4
  float* h0buf = (float*)(ws + 78970880);                 // 2048*4
  float* h1buf = (float*)(ws + 78979072);                 // 2048*4
  int*   bar   = (int*)  (ws + 78987264);
  float* out   = (float*)d_out;

  prep<<<32, 256, 0, stream>>>(bih0, bhh0, bih1, bhh1, b0, b1f, bar);
  transpose_wx<<<11520, 256, 0, stream>>>(Wih0, WxT);
  gemm_gx<<<dim3(128, 24), 256, 0, stream>>>(inV, WxT, b0, gxb);

  hipFuncSetAttribute(reinterpret_cast<const void*>(lstm_seq),
                      hipFuncAttributeMaxDynamicSharedMemorySize, LDSZ);
  KP p{Wih0, Wih1, Wlin, blin, Wmap, bmap, emb0, b1f, gxb, h0buf, h1buf, out, bar};
  void* args[] = { (void*)&p };
  hipError_t e = hipLaunchCooperativeKernel(reinterpret_cast<void*>(&lstm_seq),
                                            dim3(GWG), dim3(BTH), args, LDSZ, stream);
  if (e != hipSuccess) {
    // fallback: plain launch (1 WG/CU residency is forced by the 120.6 KB LDS footprint)
    lstm_seq<<<GWG, BTH, LDSZ, stream>>>(p);
  }
}

// Round 2
// 76815.363 us; speedup vs baseline: 1.5375x; 1.5375x over previous
//
#include <hip/hip_runtime.h>

#define GWG 256      // workgroups (1 per CU)
#define BTH 768      // threads per WG (12 waves)
#define WROW 2056    // padded LDS row pitch for Wih1 (bf16 elems)
#define LDSZ 120640

// ---------- helpers ----------
__device__ __forceinline__ unsigned short b16(float f) {   // f32 -> bf16 (RNE)
  union { float f; unsigned int i; } z; z.f = f;
  unsigned int r = z.i + 0x7fffu + ((z.i >> 16) & 1u);
  return (unsigned short)(r >> 16);
}
__device__ __forceinline__ float bup(unsigned short u) {
  union { unsigned int i; float f; } z; z.i = ((unsigned int)u) << 16; return z.f;
}
__device__ __forceinline__ float blo(unsigned int p) {
  union { unsigned int i; float f; } z; z.i = p << 16; return z.f;
}
__device__ __forceinline__ float bhi(unsigned int p) {
  union { unsigned int i; float f; } z; z.i = p & 0xffff0000u; return z.f;
}
__device__ __forceinline__ float sigm(float x) { return 1.f / (1.f + expf(-x)); }

// Coherent (agent-scope, L2-bypassing) accesses — no fences, no L2 flush.
__device__ __forceinline__ float cohL(float* p) {
  return __hip_atomic_load(p, __ATOMIC_RELAXED, __HIP_MEMORY_SCOPE_AGENT);
}
__device__ __forceinline__ void cohS(float* p, float v) {
  __hip_atomic_store(p, v, __ATOMIC_RELAXED, __HIP_MEMORY_SCOPE_AGENT);
}
__device__ __forceinline__ int cohLi(int* p) {
  return __hip_atomic_load(p, __ATOMIC_RELAXED, __HIP_MEMORY_SCOPE_AGENT);
}
__device__ __forceinline__ void cohSi(int* p, int v) {
  __hip_atomic_store(p, v, __ATOMIC_RELAXED, __HIP_MEMORY_SCOPE_AGENT);
}

// Wait until all GWG producer flags reach tgt (monotone epochs, no central counter).
__device__ __forceinline__ void waitflags(int* f, int tgt) {
  if (threadIdx.x < GWG) {
    while (cohLi(&f[threadIdx.x]) < tgt) __builtin_amdgcn_s_sleep(1);
  }
  __syncthreads();
}

// ---------- pre-kernels ----------
__global__ __launch_bounds__(256) void prep(const float* __restrict__ bih0, const float* __restrict__ bhh0,
                                            const float* __restrict__ bih1, const float* __restrict__ bhh1,
                                            float* __restrict__ b0, float* __restrict__ b1f,
                                            int* fA, int* fB, int* fY) {
  int i = blockIdx.x * 256 + threadIdx.x;
  if (i < 8192) { b0[i] = bih0[i] + bhh0[i]; b1f[i] = bih1[i] + bhh1[i]; }
  if (i < GWG) { cohSi(&fA[i], 0); cohSi(&fB[i], 0); cohSi(&fY[i], 0); }  // coherent reset (replay safety)
}

__global__ __launch_bounds__(256) void transpose_wx(const float* __restrict__ Wih0, float* __restrict__ WxT) {
  int idx = blockIdx.x * 256 + threadIdx.x;          // 360*8192 total
  int r = idx & 8191, k = idx >> 13;
  WxT[(size_t)k * 8192 + r] = Wih0[(size_t)r * 424 + k];
}

// gates_x = inputVecs @ Wx^T + b0, stored bf16, only gate rows {i,g,o}
__global__ __launch_bounds__(256) void gemm_gx(const float* __restrict__ inV, const float* __restrict__ WxT,
                                               const float* __restrict__ b0, unsigned short* __restrict__ gxb) {
  __shared__ float lin[32 * 360];
  int t0 = blockIdx.x * 32;
  int by = blockIdx.y;                 // 0..23
  int ry = by >> 3;
  int gatey = ry + (ry ? 1 : 0);       // {0,2,3}
  int r = gatey * 2048 + (by & 7) * 256 + threadIdx.x;
  for (int i = threadIdx.x; i < 32 * 360; i += 256) lin[i] = inV[(size_t)t0 * 360 + i];
  __syncthreads();
  float b = b0[r];
  float acc[32];
#pragma unroll
  for (int tt = 0; tt < 32; ++tt) acc[tt] = b;
  for (int k = 0; k < 360; k += 4) {
    float w0 = WxT[(size_t)(k + 0) * 8192 + r];
    float w1 = WxT[(size_t)(k + 1) * 8192 + r];
    float w2 = WxT[(size_t)(k + 2) * 8192 + r];
    float w3 = WxT[(size_t)(k + 3) * 8192 + r];
#pragma unroll
    for (int tt = 0; tt < 32; ++tt) {
      float4 l = *reinterpret_cast<const float4*>(&lin[tt * 360 + k]);
      acc[tt] = fmaf(w0, l.x, fmaf(w1, l.y, fmaf(w2, l.z, fmaf(w3, l.w, acc[tt]))));
    }
  }
  for (int tt = 0; tt < 32; ++tt) gxb[(size_t)(t0 + tt) * 8192 + r] = b16(acc[tt]);
}

// ---------- persistent scan kernel ----------
struct KP {
  const float* Wih0; const float* Wih1; const float* Wlin; const float* blin;
  const float* Wmap; const float* bmap; const float* embed0; const float* b1f;
  const unsigned short* gxb;
  float* h0buf; float* h1buf; float* ybuf; float* out;
  int* fA; int* fB; int* fY;
};

__global__ __launch_bounds__(BTH) void lstm_seq(KP p) {
  extern __shared__ __align__(16) char smem[];
  unsigned short* lW1 = (unsigned short*)smem;                  // 24 x WROW   (Wih1 slice)
  unsigned short* lWe = (unsigned short*)(smem + 98688);        // 24 x 64     (We slice)
  unsigned short* lWl = (unsigned short*)(smem + 101760);       // 2 x 2048    (Wlin rows)
  float* lH = (float*)(smem + 109952);                          // 2048 (h0 / h1)
  float* lY = (float*)(smem + 118144);                          // 512
  float* lE = (float*)(smem + 120192);                          // 64
  float* lR = (float*)(smem + 120448);                          // 24 (+pad)
  float* lV = (float*)(smem + 120576);                          // 16

  const int w = blockIdx.x, tid = threadIdx.x;
  const int rl = tid >> 5;          // 0..23 (row within WG)
  const int l32 = tid & 31;
  const int g3 = rl >> 3;
  const int gate = g3 + (g3 ? 1 : 0);      // {0,2,3} = i,g,o
  const int gr = w * 8 + (rl & 7) + 2048 * gate;

  // ---- stage weights into LDS (once) ----
  for (int r2 = 0; r2 < 24; ++r2) {
    int gg = r2 >> 3; int grr = w * 8 + (r2 & 7) + 2048 * (gg + (gg ? 1 : 0));
    const float* src = p.Wih1 + (size_t)grr * 2048;
    for (int i = tid; i < 2048; i += BTH) lW1[r2 * WROW + i] = b16(src[i]);
  }
  for (int i = tid; i < 24 * 64; i += BTH) {
    int r2 = i >> 6, k = i & 63; int gg = r2 >> 3;
    int grr = w * 8 + (r2 & 7) + 2048 * (gg + (gg ? 1 : 0));
    lWe[r2 * 64 + k] = b16(p.Wih0[(size_t)grr * 424 + 360 + k]);
  }
  for (int i = tid; i < 2 * 2048; i += BTH) {
    int q = i >> 11, k = i & 2047;
    lWl[i] = b16(p.Wlin[(size_t)(w * 2 + q) * 2048 + k]);
  }
  unsigned int wm[32];               // Wmap fragment in VGPRs (pre-rotated)
  float bm = 0.f, rswp = 0.f;        // rswp: per-thread partial rowsum of Wmap
  {
    int e = tid >> 3, l8 = tid & 7;
    if (tid < 512) {
      bm = p.bmap[e];
#pragma unroll
      for (int i = 0; i < 32; ++i) {
        int ii = (i + l8 * 4) & 31;
        int k = e * 512 + l8 * 64 + 2 * ii;
        wm[i] = ((unsigned int)b16(p.Wmap[k + 1]) << 16) | (unsigned int)b16(p.Wmap[k]);
        rswp += blo(wm[i]) + bhi(wm[i]);
      }
    } else {
#pragma unroll
      for (int i = 0; i < 32; ++i) wm[i] = 0u;
    }
  }
  const float b1r = p.b1f[gr];
  const float bl0 = p.blin[w * 2], bl1 = p.blin[w * 2 + 1];
  __syncthreads();

  for (int t = 0; t < 4096; ++t) {
    const int cur = t & 1;
    // ---------- phase H0: lse + embed (redundant) + gates0 ----------
    if (t == 0) {
      if (tid < 64) lE[tid] = p.embed0[tid];
      __syncthreads();
    } else {
      waitflags(p.fY, t);                       // y(t-1) produced by all WGs
      float yv = 0.f;
      if (tid < 512) { yv = cohL(&p.ybuf[((t - 1) & 1) * 512 + tid]); lY[tid] = yv; }
      float m = -1e30f, s = 0.f;
      if (tid < 512) {
        m = yv;
#pragma unroll
        for (int d = 1; d < 64; d <<= 1) m = fmaxf(m, __shfl_xor(m, d));
        if ((tid & 63) == 0) lV[tid >> 6] = m;
      }
      __syncthreads();
      m = fmaxf(fmaxf(fmaxf(lV[0], lV[1]), fmaxf(lV[2], lV[3])),
                fmaxf(fmaxf(lV[4], lV[5]), fmaxf(lV[6], lV[7])));
      if (tid < 512) {
        s = expf(yv - m);
#pragma unroll
        for (int d = 1; d < 64; d <<= 1) s += __shfl_xor(s, d);
      }
      __syncthreads();
      if (tid < 512 && (tid & 63) == 0) lV[tid >> 6] = s;
      __syncthreads();
      float lse = m + logf(lV[0] + lV[1] + lV[2] + lV[3] + lV[4] + lV[5] + lV[6] + lV[7]);
      // embed = Wmap@y - lse*rowsum(Wmap) + bmap
      if (tid < 512) {
        int l8 = tid & 7, base = l8 * 64;
        float acc = 0.f;
#pragma unroll
        for (int i = 0; i < 32; ++i) {
          int k = base + 2 * ((i + l8 * 4) & 31);
          float2 yv2 = *(const float2*)&lY[k];
          acc = fmaf(blo(wm[i]), yv2.x, fmaf(bhi(wm[i]), yv2.y, acc));
        }
        acc -= lse * rswp;
        acc += __shfl_xor(acc, 1); acc += __shfl_xor(acc, 2); acc += __shfl_xor(acc, 4);
        if (l8 == 0) lE[tid >> 3] = acc + bm;
      }
      __syncthreads();
    }
    // gates0 -> h0 (8 values per WG)
    {
      unsigned int uwp = *(const unsigned int*)&lWe[rl * 64 + l32 * 2];
      float2 ev = *(const float2*)&lE[l32 * 2];
      float a = fmaf(blo(uwp), ev.x, bhi(uwp) * ev.y);
      a += __shfl_xor(a, 1); a += __shfl_xor(a, 2); a += __shfl_xor(a, 4);
      a += __shfl_xor(a, 8); a += __shfl_xor(a, 16);
      if (l32 == 0) lR[rl] = a + bup(p.gxb[(size_t)t * 8192 + gr]);
    }
    __syncthreads();
    if (tid < 8) {
      float c = sigm(lR[tid]) * tanhf(lR[8 + tid]);
      float h = sigm(lR[16 + tid]) * tanhf(c);
      cohS(&p.h0buf[cur * 2048 + w * 8 + tid], h);
    }
    if (tid == 0) {                              // data stores are in wave 0 -> vmcnt covers them
      asm volatile("s_waitcnt vmcnt(0)" ::: "memory");
      cohSi(&p.fA[w], t + 1);
    }
    // ---------- phase H1: gates1 -> h1 ----------
    waitflags(p.fA, t + 1);
    if (tid < 512) {
      float* src = &p.h0buf[cur * 2048 + tid * 4];
      float* dst = &lH[tid * 4];
      dst[0] = cohL(src); dst[1] = cohL(src + 1); dst[2] = cohL(src + 2); dst[3] = cohL(src + 3);
    }
    __syncthreads();
    {
      float acc = 0.f;
      const unsigned short* wr = lW1 + rl * WROW;
#pragma unroll 4
      for (int mm = 0; mm < 16; ++mm) {
        int k = l32 * 4 + mm * 128;
        ushort4 uw = *(const ushort4*)&wr[k];
        float4 hv = *(const float4*)&lH[k];
        acc = fmaf(bup(uw.x), hv.x, acc);
        acc = fmaf(bup(uw.y), hv.y, acc);
        acc = fmaf(bup(uw.z), hv.z, acc);
        acc = fmaf(bup(uw.w), hv.w, acc);
      }
      acc += __shfl_xor(acc, 1); acc += __shfl_xor(acc, 2); acc += __shfl_xor(acc, 4);
      acc += __shfl_xor(acc, 8); acc += __shfl_xor(acc, 16);
      if (l32 == 0) lR[rl] = acc + b1r;
    }
    __syncthreads();
    if (tid < 8) {
      float c = sigm(lR[tid]) * tanhf(lR[8 + tid]);
      float h = sigm(lR[16 + tid]) * tanhf(c);
      cohS(&p.h1buf[cur * 2048 + w * 8 + tid], h);
    }
    if (tid == 0) {
      asm volatile("s_waitcnt vmcnt(0)" ::: "memory");
      cohSi(&p.fB[w], t + 1);
    }
    // ---------- phase Y: y = Wlin @ h1 + blin (2 rows per WG) ----------
    waitflags(p.fB, t + 1);
    if (tid < 512) {
      float* src = &p.h1buf[cur * 2048 + tid * 4];
      float* dst = &lH[tid * 4];
      dst[0] = cohL(src); dst[1] = cohL(src + 1); dst[2] = cohL(src + 2); dst[3] = cohL(src + 3);
    }
    __syncthreads();
    if (tid < 512) {
      int q = tid >> 8, l = tid & 255;
      float a = 0.f;
#pragma unroll
      for (int c2 = 0; c2 < 2; ++c2) {
        int k = c2 * 1024 + l * 4;
        ushort4 uw = *(const ushort4*)&lWl[q * 2048 + k];
        float4 hv = *(const float4*)&lH[k];
        a = fmaf(bup(uw.x), hv.x, fmaf(bup(uw.y), hv.y, fmaf(bup(uw.z), hv.z, fmaf(bup(uw.w), hv.w, a))));
      }
#pragma unroll
      for (int d = 1; d < 64; d <<= 1) a += __shfl_xor(a, d);
      if ((tid & 63) == 0) lV[tid >> 6] = a;
    }
    __syncthreads();
    if (tid < 2) {
      float y = lV[tid * 4] + lV[tid * 4 + 1] + lV[tid * 4 + 2] + lV[tid * 4 + 3] + (tid ? bl1 : bl0);
      p.out[(size_t)t * 512 + w * 2 + tid] = y;          // plain store: never re-read
      cohS(&p.ybuf[cur * 512 + w * 2 + tid], y);
    }
    if (tid == 0) {
      asm volatile("s_waitcnt vmcnt(0)" ::: "memory");
      cohSi(&p.fY[w], t + 1);
    }
  }
}

// ---------- host ----------
extern "C" void kernel_launch(void* const* d_in, const int* in_sizes, int n_in,
                              void* d_out, int out_size, void* d_ws, size_t ws_size,
                              hipStream_t stream) {
  const float* inV  = (const float*)d_in[0];
  const float* Wih0 = (const float*)d_in[1];
  const float* bih0 = (const float*)d_in[2];
  const float* bhh0 = (const float*)d_in[3];
  const float* Wih1 = (const float*)d_in[4];
  const float* bih1 = (const float*)d_in[5];
  const float* bhh1 = (const float*)d_in[6];
  const float* Wlin = (const float*)d_in[7];
  const float* blin = (const float*)d_in[8];
  const float* Wmap = (const float*)d_in[9];
  const float* bmap = (const float*)d_in[10];
  const float* emb0 = (const float*)d_in[11];

  char* ws = (char*)d_ws;
  unsigned short* gxb = (unsigned short*)(ws);            // 67,108,864 B
  float* WxT   = (float*)(ws + 67108864);                 // 11,796,480 B
  float* b0    = (float*)(ws + 78905344);                 // 32 KB
  float* b1f   = (float*)(ws + 78938112);                 // 32 KB
  float* h0buf = (float*)(ws + 78970880);                 // 2*2048*4 = 16 KB
  float* h1buf = (float*)(ws + 78987264);                 // 16 KB
  float* ybuf  = (float*)(ws + 79003648);                 // 2*512*4 = 4 KB
  int*   fA    = (int*)  (ws + 79007744);                 // 1 KB
  int*   fB    = (int*)  (ws + 79008768);                 // 1 KB
  int*   fY    = (int*)  (ws + 79009792);                 // 1 KB
  float* out   = (float*)d_out;

  prep<<<32, 256, 0, stream>>>(bih0, bhh0, bih1, bhh1, b0, b1f, fA, fB, fY);
  transpose_wx<<<11520, 256, 0, stream>>>(Wih0, WxT);
  gemm_gx<<<dim3(128, 24), 256, 0, stream>>>(inV, WxT, b0, gxb);

  hipFuncSetAttribute(reinterpret_cast<const void*>(lstm_seq),
                      hipFuncAttributeMaxDynamicSharedMemorySize, LDSZ);
  KP p{Wih0, Wih1, Wlin, blin, Wmap, bmap, emb0, b1f, gxb, h0buf, h1buf, ybuf, out, fA, fB, fY};
  void* args[] = { (void*)&p };
  hipError_t e = hipLaunchCooperativeKernel(reinterpret_cast<void*>(&lstm_seq),
                                            dim3(GWG), dim3(BTH), args, LDSZ, stream);
  if (e != hipSuccess) {
    lstm_seq<<<GWG, BTH, LDSZ, stream>>>(p);
  }
}

// Round 3
// 72391.339 us; speedup vs baseline: 1.6315x; 1.0611x over previous
//
#include <hip/hip_runtime.h>

#define GWG 256      // workgroups (1 per CU)
#define BTH 768      // threads per WG (12 waves)
#define WROW 2056    // padded LDS row pitch for Wih1 (bf16 elems)
#define LDSZ 120640

typedef float f4v __attribute__((ext_vector_type(4)));
typedef int   i4v __attribute__((ext_vector_type(4)));

// ---------- helpers ----------
__device__ __forceinline__ unsigned short b16(float f) {   // f32 -> bf16 (RNE)
  union { float f; unsigned int i; } z; z.f = f;
  unsigned int r = z.i + 0x7fffu + ((z.i >> 16) & 1u);
  return (unsigned short)(r >> 16);
}
__device__ __forceinline__ float bup(unsigned short u) {
  union { unsigned int i; float f; } z; z.i = ((unsigned int)u) << 16; return z.f;
}
__device__ __forceinline__ float blo(unsigned int p) {
  union { unsigned int i; float f; } z; z.i = p << 16; return z.f;
}
__device__ __forceinline__ float bhi(unsigned int p) {
  union { unsigned int i; float f; } z; z.i = p & 0xffff0000u; return z.f;
}
__device__ __forceinline__ float sigm(float x) { return 1.f / (1.f + expf(-x)); }

// scalar coherent (agent-scope) ops — flags & tiny stores
__device__ __forceinline__ void cohS(float* p, float v) {
  __hip_atomic_store(p, v, __ATOMIC_RELAXED, __HIP_MEMORY_SCOPE_AGENT);
}
__device__ __forceinline__ int cohLi(int* p) {
  return __hip_atomic_load(p, __ATOMIC_RELAXED, __HIP_MEMORY_SCOPE_AGENT);
}
__device__ __forceinline__ void cohSi(int* p, int v) {
  __hip_atomic_store(p, v, __ATOMIC_RELAXED, __HIP_MEMORY_SCOPE_AGENT);
}

// wide coherent poll: wave 0 covers 256 flags with 64 dwordx4 loads
__device__ __forceinline__ void waitflags4(int* f, int tgt) {
  if (threadIdx.x < 64) {
    const int* q = f + threadIdx.x * 4;
    for (;;) {
      i4v v;
      asm volatile("global_load_dwordx4 %0, %1, off sc0 sc1\n\ts_waitcnt vmcnt(0)"
                   : "=v"(v) : "v"(q) : "memory");
      int mn0 = v[0] < v[1] ? v[0] : v[1];
      int mn1 = v[2] < v[3] ? v[2] : v[3];
      int mn = mn0 < mn1 ? mn0 : mn1;
      if (__all(mn >= tgt)) break;
      __builtin_amdgcn_s_sleep(2);
    }
  }
  __syncthreads();
}

// ---------- pre-kernels ----------
__global__ __launch_bounds__(256) void prep(const float* __restrict__ bih0, const float* __restrict__ bhh0,
                                            const float* __restrict__ bih1, const float* __restrict__ bhh1,
                                            const float* __restrict__ blin,
                                            float* __restrict__ b0, float* __restrict__ b1f,
                                            float* ybuf, int* fH, int* fY) {
  int i = blockIdx.x * 256 + threadIdx.x;
  if (i < 8192) { b0[i] = bih0[i] + bhh0[i]; b1f[i] = bih1[i] + bhh1[i]; }
  if (i < GWG) { cohSi(&fH[i], 0); cohSi(&fY[i], 0); }
  if (i < 512) {                         // seed all 4 y-accumulators with blin (coherent: replay-safe)
    float b = blin[i];
#pragma unroll
    for (int bq = 0; bq < 4; ++bq) cohS(&ybuf[bq * 512 + i], b);
  }
}

__global__ __launch_bounds__(256) void transpose_wx(const float* __restrict__ Wih0, float* __restrict__ WxT) {
  int idx = blockIdx.x * 256 + threadIdx.x;          // 360*8192 total
  int r = idx & 8191, k = idx >> 13;
  WxT[(size_t)k * 8192 + r] = Wih0[(size_t)r * 424 + k];
}

// gates_x = inputVecs @ Wx^T + b0, stored bf16, only gate rows {i,g,o}
__global__ __launch_bounds__(256) void gemm_gx(const float* __restrict__ inV, const float* __restrict__ WxT,
                                               const float* __restrict__ b0, unsigned short* __restrict__ gxb) {
  __shared__ float lin[32 * 360];
  int t0 = blockIdx.x * 32;
  int by = blockIdx.y;                 // 0..23
  int ry = by >> 3;
  int gatey = ry + (ry ? 1 : 0);       // {0,2,3}
  int r = gatey * 2048 + (by & 7) * 256 + threadIdx.x;
  for (int i = threadIdx.x; i < 32 * 360; i += 256) lin[i] = inV[(size_t)t0 * 360 + i];
  __syncthreads();
  float b = b0[r];
  float acc[32];
#pragma unroll
  for (int tt = 0; tt < 32; ++tt) acc[tt] = b;
  for (int k = 0; k < 360; k += 4) {
    float w0 = WxT[(size_t)(k + 0) * 8192 + r];
    float w1 = WxT[(size_t)(k + 1) * 8192 + r];
    float w2 = WxT[(size_t)(k + 2) * 8192 + r];
    float w3 = WxT[(size_t)(k + 3) * 8192 + r];
#pragma unroll
    for (int tt = 0; tt < 32; ++tt) {
      float4 l = *reinterpret_cast<const float4*>(&lin[tt * 360 + k]);
      acc[tt] = fmaf(w0, l.x, fmaf(w1, l.y, fmaf(w2, l.z, fmaf(w3, l.w, acc[tt]))));
    }
  }
  for (int tt = 0; tt < 32; ++tt) gxb[(size_t)(t0 + tt) * 8192 + r] = b16(acc[tt]);
}

// ---------- persistent scan kernel ----------
struct KP {
  const float* Wih0; const float* Wih1; const float* Wlin;
  const float* Wmap; const float* bmap; const float* embed0; const float* b1f;
  const float* blin;
  const unsigned short* gxb;
  float* h0buf; float* ybuf; float* out;
  int* fH; int* fY;
};

__global__ __launch_bounds__(BTH) void lstm_seq(KP p) {
  extern __shared__ __align__(16) char smem[];
  unsigned short* lW1 = (unsigned short*)smem;                  // 24 x WROW  (Wih1 slice)        @0
  unsigned short* lWe = (unsigned short*)(smem + 98688);        // 24 x 64    (We slice)
  unsigned short* lWc = (unsigned short*)(smem + 101760);       // 8 x 512    (Wlin cols 8w..8w+7)
  float* lH  = (float*)(smem + 109952);                         // 2048 (h0 gather)
  float* lY  = (float*)(smem + 118144);                         // 512  (y)
  float* lE  = (float*)(smem + 120192);                         // 64   (embed)
  float* lR  = (float*)(smem + 120448);                         // 24+pad (gate pre-act)
  float* lH1 = (float*)(smem + 120576);                         // 8    (h1 local)
  float* lV  = (float*)(smem + 120608);                         // 8    (reduce staging)

  const int w = blockIdx.x, tid = threadIdx.x;
  const int rl = tid >> 5;          // 0..23 (gate-row within WG)
  const int l32 = tid & 31;
  const int g3 = rl >> 3;
  const int gate = g3 + (g3 ? 1 : 0);      // {0,2,3} = i,g,o
  const int gr = w * 8 + (rl & 7) + 2048 * gate;

  // ---- stage weights into LDS (once) ----
  for (int r2 = 0; r2 < 24; ++r2) {
    int gg = r2 >> 3; int grr = w * 8 + (r2 & 7) + 2048 * (gg + (gg ? 1 : 0));
    const float* src = p.Wih1 + (size_t)grr * 2048;
    for (int i = tid; i < 2048; i += BTH) lW1[r2 * WROW + i] = b16(src[i]);
  }
  for (int i = tid; i < 24 * 64; i += BTH) {
    int r2 = i >> 6, k = i & 63; int gg = r2 >> 3;
    int grr = w * 8 + (r2 & 7) + 2048 * (gg + (gg ? 1 : 0));
    lWe[r2 * 64 + k] = b16(p.Wih0[(size_t)grr * 424 + 360 + k]);
  }
  for (int i = tid; i < 8 * 512; i += BTH) {       // Wlin columns 8w..8w+7
    int j = i >> 9, r = i & 511;
    lWc[j * 512 + r] = b16(p.Wlin[(size_t)r * 2048 + w * 8 + j]);
  }
  unsigned int wm[32];               // Wmap fragment in VGPRs (pre-rotated)
  float bm = 0.f, rswp = 0.f;        // rswp: per-thread partial rowsum of Wmap
  {
    int e = tid >> 3, l8 = tid & 7;
    if (tid < 512) {
      bm = p.bmap[e];
#pragma unroll
      for (int i = 0; i < 32; ++i) {
        int ii = (i + l8 * 4) & 31;
        int k = e * 512 + l8 * 64 + 2 * ii;
        wm[i] = ((unsigned int)b16(p.Wmap[k + 1]) << 16) | (unsigned int)b16(p.Wmap[k]);
        rswp += blo(wm[i]) + bhi(wm[i]);
      }
    } else {
#pragma unroll
      for (int i = 0; i < 32; ++i) wm[i] = 0u;
    }
  }
  const float b1r = p.b1f[gr];
  const float bl0 = p.blin[w * 2], bl1 = p.blin[w * 2 + 1];
  __syncthreads();

  for (int t = 0; t < 4096; ++t) {
    const int cur = t & 1;
    // prefetch gx(t) — flag-independent, hides under the poll
    const unsigned short gxu = p.gxb[(size_t)t * 8192 + gr];
    // ================= phase A: lse + embed + h0 =================
    if (t == 0) {
      if (tid < 64) lE[tid] = p.embed0[tid];
      __syncthreads();
    } else {
      waitflags4(p.fY, t);                       // all partial-y(t-1) accumulated
      f4v yv4 = {};
      const float* ysrc = &p.ybuf[((t - 1) & 3) * 512 + (tid & 127) * 4];
      if (tid < 128)
        asm volatile("global_load_dwordx4 %0, %1, off sc0 sc1" : "=v"(yv4) : "v"(ysrc) : "memory");
      asm volatile("s_waitcnt vmcnt(0)" ::: "memory");
      __builtin_amdgcn_sched_barrier(0);
      if (tid < 128) *(f4v*)&lY[tid * 4] = yv4;
      __syncthreads();
      // write out(t-1) slice; reset buffer (t+1)&3 to blin (h-b chain makes this safe)
      if (tid < 2) p.out[(size_t)(t - 1) * 512 + w * 2 + tid] = lY[w * 2 + tid];
      if (tid == 8) cohS(&p.ybuf[((t - 3) & 3) * 512 + w * 2], bl0);
      if (tid == 9) cohS(&p.ybuf[((t - 3) & 3) * 512 + w * 2 + 1], bl1);
      // lse over 512 (redundant per WG)
      float yv = 0.f, m = -1e30f;
      if (tid < 512) {
        yv = lY[tid]; m = yv;
#pragma unroll
        for (int d = 1; d < 64; d <<= 1) m = fmaxf(m, __shfl_xor(m, d));
        if ((tid & 63) == 0) lV[tid >> 6] = m;
      }
      __syncthreads();
      m = fmaxf(fmaxf(fmaxf(lV[0], lV[1]), fmaxf(lV[2], lV[3])),
                fmaxf(fmaxf(lV[4], lV[5]), fmaxf(lV[6], lV[7])));
      float s = 0.f;
      if (tid < 512) {
        s = expf(yv - m);
#pragma unroll
        for (int d = 1; d < 64; d <<= 1) s += __shfl_xor(s, d);
      }
      __syncthreads();
      if (tid < 512 && (tid & 63) == 0) lV[tid >> 6] = s;
      __syncthreads();
      float lse = m + logf(lV[0] + lV[1] + lV[2] + lV[3] + lV[4] + lV[5] + lV[6] + lV[7]);
      // embed = Wmap@y - lse*rowsum(Wmap) + bmap
      if (tid < 512) {
        int l8 = tid & 7, base = l8 * 64;
        float acc = 0.f;
#pragma unroll
        for (int i = 0; i < 32; ++i) {
          int k = base + 2 * ((i + l8 * 4) & 31);
          float2 yv2 = *(const float2*)&lY[k];
          acc = fmaf(blo(wm[i]), yv2.x, fmaf(bhi(wm[i]), yv2.y, acc));
        }
        acc -= lse * rswp;
        acc += __shfl_xor(acc, 1); acc += __shfl_xor(acc, 2); acc += __shfl_xor(acc, 4);
        if (l8 == 0) lE[tid >> 3] = acc + bm;
      }
      __syncthreads();
    }
    // gates0: rows {i,g,o} x 8, via We@embed (shuffle) + gx
    {
      unsigned int uwp = *(const unsigned int*)&lWe[rl * 64 + l32 * 2];
      float2 ev = *(const float2*)&lE[l32 * 2];
      float a = fmaf(blo(uwp), ev.x, bhi(uwp) * ev.y);
      a += __shfl_xor(a, 1); a += __shfl_xor(a, 2); a += __shfl_xor(a, 4);
      a += __shfl_xor(a, 8); a += __shfl_xor(a, 16);
      if (l32 == 0) lR[rl] = a + bup(gxu);
    }
    __syncthreads();
    if (tid < 8) {
      float c = sigm(lR[tid]) * tanhf(lR[8 + tid]);
      float h = sigm(lR[16 + tid]) * tanhf(c);
      cohS(&p.h0buf[cur * 2048 + w * 8 + tid], h);
    }
    if (tid == 0) {                      // all phase-A stores are wave 0 -> one drain covers them
      asm volatile("s_waitcnt vmcnt(0)" ::: "memory");
      cohSi(&p.fH[w], t + 1);
    }
    // ================= phase B: h1 + partial y =================
    waitflags4(p.fH, t + 1);
    {
      f4v hv4 = {};
      const float* hsrc = &p.h0buf[cur * 2048 + (tid & 511) * 4];
      if (tid < 512)
        asm volatile("global_load_dwordx4 %0, %1, off sc0 sc1" : "=v"(hv4) : "v"(hsrc) : "memory");
      asm volatile("s_waitcnt vmcnt(0)" ::: "memory");
      __builtin_amdgcn_sched_barrier(0);
      if (tid < 512) *(f4v*)&lH[tid * 4] = hv4;
    }
    __syncthreads();
    {
      float acc = 0.f;
      const unsigned short* wr = lW1 + rl * WROW;
#pragma unroll 4
      for (int mm = 0; mm < 16; ++mm) {
        int k = l32 * 4 + mm * 128;
        ushort4 uw = *(const ushort4*)&wr[k];
        float4 hv = *(const float4*)&lH[k];
        acc = fmaf(bup(uw.x), hv.x, acc);
        acc = fmaf(bup(uw.y), hv.y, acc);
        acc = fmaf(bup(uw.z), hv.z, acc);
        acc = fmaf(bup(uw.w), hv.w, acc);
      }
      acc += __shfl_xor(acc, 1); acc += __shfl_xor(acc, 2); acc += __shfl_xor(acc, 4);
      acc += __shfl_xor(acc, 8); acc += __shfl_xor(acc, 16);
      if (l32 == 0) lR[rl] = acc + b1r;
    }
    __syncthreads();
    if (tid < 8) {
      float c = sigm(lR[tid]) * tanhf(lR[8 + tid]);
      lH1[tid] = sigm(lR[16 + tid]) * tanhf(c);
    }
    __syncthreads();
    if (tid < 512) {                 // partial y from local 8 h1 values -> global atomic accumulate
      float yp = 0.f;
#pragma unroll
      for (int j = 0; j < 8; ++j) yp = fmaf(bup(lWc[j * 512 + tid]), lH1[j], yp);
      __hip_atomic_fetch_add(&p.ybuf[(t & 3) * 512 + tid], yp,
                             __ATOMIC_RELAXED, __HIP_MEMORY_SCOPE_AGENT);
    }
    asm volatile("s_waitcnt vmcnt(0)" ::: "memory");   // every wave drains its own atomics
    __syncthreads();
    if (tid == 0) cohSi(&p.fY[w], t + 1);
  }
  // epilogue: publish out[4095]
  waitflags4(p.fY, 4096);
  {
    f4v yv4 = {};
    const float* ysrc = &p.ybuf[3 * 512 + (tid & 127) * 4];
    if (tid < 128)
      asm volatile("global_load_dwordx4 %0, %1, off sc0 sc1" : "=v"(yv4) : "v"(ysrc) : "memory");
    asm volatile("s_waitcnt vmcnt(0)" ::: "memory");
    __builtin_amdgcn_sched_barrier(0);
    if (tid < 128) *(f4v*)&lY[tid * 4] = yv4;
  }
  __syncthreads();
  if (tid < 2) p.out[(size_t)4095 * 512 + w * 2 + tid] = lY[w * 2 + tid];
}

// ---------- host ----------
extern "C" void kernel_launch(void* const* d_in, const int* in_sizes, int n_in,
                              void* d_out, int out_size, void* d_ws, size_t ws_size,
                              hipStream_t stream) {
  const float* inV  = (const float*)d_in[0];
  const float* Wih0 = (const float*)d_in[1];
  const float* bih0 = (const float*)d_in[2];
  const float* bhh0 = (const float*)d_in[3];
  const float* Wih1 = (const float*)d_in[4];
  const float* bih1 = (const float*)d_in[5];
  const float* bhh1 = (const float*)d_in[6];
  const float* Wlin = (const float*)d_in[7];
  const float* blin = (const float*)d_in[8];
  const float* Wmap = (const float*)d_in[9];
  const float* bmap = (const float*)d_in[10];
  const float* emb0 = (const float*)d_in[11];

  char* ws = (char*)d_ws;
  unsigned short* gxb = (unsigned short*)(ws);            // 67,108,864 B
  float* WxT   = (float*)(ws + 67108864);                 // 11,796,480 B
  float* b0    = (float*)(ws + 78905344);                 // 32 KB
  float* b1f   = (float*)(ws + 78938112);                 // 32 KB
  float* h0buf = (float*)(ws + 78970880);                 // 2*2048*4 = 16 KB
  float* ybuf  = (float*)(ws + 78987264);                 // 4*512*4  =  8 KB
  int*   fH    = (int*)  (ws + 78995456);                 // 1 KB
  int*   fY    = (int*)  (ws + 78996480);                 // 1 KB
  float* out   = (float*)d_out;

  prep<<<32, 256, 0, stream>>>(bih0, bhh0, bih1, bhh1, blin, b0, b1f, ybuf, fH, fY);
  transpose_wx<<<11520, 256, 0, stream>>>(Wih0, WxT);
  gemm_gx<<<dim3(128, 24), 256, 0, stream>>>(inV, WxT, b0, gxb);

  hipFuncSetAttribute(reinterpret_cast<const void*>(lstm_seq),
                      hipFuncAttributeMaxDynamicSharedMemorySize, LDSZ);
  KP p{Wih0, Wih1, Wlin, Wmap, bmap, emb0, b1f, blin, gxb, h0buf, ybuf, out, fH, fY};
  void* args[] = { (void*)&p };
  hipError_t e = hipLaunchCooperativeKernel(reinterpret_cast<void*>(&lstm_seq),
                                            dim3(GWG), dim3(BTH), args, LDSZ, stream);
  if (e != hipSuccess) {
    lstm_seq<<<GWG, BTH, LDSZ, stream>>>(p);
  }
}